// Round 2
// baseline (229.367 us; speedup 1.0000x reference)
//
#include <hip/hip_runtime.h>
#include <hip/hip_bf16.h>

#define NB 512     // birds
#define NC 512     // colors
#define HD 128     // hidden
#define NN 1024    // total nodes

// ---------------------------------------------------------------------------
// Rank-based per-row descending argsort (exact lax.top_k semantics:
// descending value, ties -> lower index first). One pass, O(N^2) broadcast
// compares in LDS. rank[t] = #{j: p[j]>p[t]} + #{j<t: p[j]==p[t]}.
// ---------------------------------------------------------------------------
__global__ void k_sort(const float* __restrict__ probs, int* __restrict__ idx) {
  __shared__ float s[NC];
  const int row = blockIdx.x;
  const int t = threadIdx.x;              // 512 threads, one element each
  s[t] = probs[row * NC + t];
  __syncthreads();
  const float myv = s[t];
  int rank = 0;
#pragma unroll 8
  for (int j = 0; j < NC; ++j) {
    float sv = s[j];
    rank += (sv > myv) || (sv == myv && j < t);
  }
  idx[row * NC + rank] = t;
}

// ---------------------------------------------------------------------------
// Init: x0 (all 1024 node features) + u/v for layer 0, fused.
// Blocks 0..63: bird rows (8 each). Blocks 64..127: color rows (8 each).
// 512 threads = 128 cols x 4 row-slots; each slot covers rows rs, rs+4.
// ---------------------------------------------------------------------------
__global__ void k_init(const float* __restrict__ probs, const float* __restrict__ npw,
                       const float* __restrict__ npb, const float* __restrict__ ew1,
                       const float* __restrict__ eb1, float* __restrict__ x0,
                       float* __restrict__ u, float* __restrict__ v) {
  __shared__ float ap[8][NC];   // 16 KB, bird path only
  __shared__ float xs[8][HD];   // 4 KB
  const int n = threadIdx.x & 127, rs4 = threadIdx.x >> 7;

  if (blockIdx.x < 64) {        // ---- bird rows ----
    const int r0 = blockIdx.x * 8;
    for (int t = threadIdx.x; t < 8 * NC; t += 512)
      ap[t >> 9][t & 511] = probs[(r0 + (t >> 9)) * NC + (t & 511)];
    __syncthreads();
    for (int rr = rs4; rr < 8; rr += 4) {
      float acc = npb[n];
      for (int k = 0; k < NC; ++k)
        acc += ap[rr][k] * npw[k * HD + n];
      x0[(r0 + rr) * HD + n] = acc;
      xs[rr][n] = acc;
    }
    __syncthreads();
    for (int rr = rs4; rr < 8; rr += 4) {
      float acc = eb1[n];
      for (int k = 0; k < HD; ++k)
        acc += xs[rr][k] * ew1[k * HD + n];
      u[(r0 + rr) * HD + n] = acc;
    }
  } else {                      // ---- color rows ----
    const int c0 = (blockIdx.x - 64) * 8;
    for (int rr = rs4; rr < 8; rr += 4) {
      float val = npw[(c0 + rr) * HD + n] + npb[n];
      x0[(NB + c0 + rr) * HD + n] = val;
      xs[rr][n] = val;
    }
    __syncthreads();
    for (int rr = rs4; rr < 8; rr += 4) {
      float acc = 0.0f;
      for (int k = 0; k < HD; ++k)
        acc += xs[rr][k] * ew1[(HD + k) * HD + n];
      v[(c0 + rr) * HD + n] = acc;
    }
  }
}

// ---------------------------------------------------------------------------
// R_i[h] = sum_j relu(u_i[h]+v_j[h]);  S_j[h] = sum_i relu(u_i[h]+v_j[h])
// 256 blocks x 256 threads, 4 rows/block (proven in round 1).
// ---------------------------------------------------------------------------
__global__ void k_RS(const float* __restrict__ u, const float* __restrict__ v,
                     float* __restrict__ RS) {
  const int b = blockIdx.x;
  const int h = threadIdx.x & 127, rr = threadIdx.x >> 7;
  const float *mine, *other;
  int r0, outbase;
  if (b < 128) { mine = u; other = v; r0 = b * 4;         outbase = r0; }
  else         { mine = v; other = u; r0 = (b - 128) * 4; outbase = NB + r0; }
  const float base0 = mine[(r0 + rr) * HD + h];
  const float base1 = mine[(r0 + rr + 2) * HD + h];
  float acc0 = 0.f, acc1 = 0.f;
#pragma unroll 4
  for (int j = 0; j < 512; ++j) {
    float ov = other[j * HD + h];
    acc0 += fmaxf(base0 + ov, 0.f);
    acc1 += fmaxf(base1 + ov, 0.f);
  }
  RS[(outbase + rr) * HD + h]     = acc0;
  RS[(outbase + rr + 2) * HD + h] = acc1;
}

// ---------------------------------------------------------------------------
// Per-layer fused: aggr = RS@ew2 + 512*eb2; xout = node-MLP([x,aggr]);
// u/v for the NEXT layer from xout. 128 blocks x 512 threads, 8 rows each.
// ---------------------------------------------------------------------------
__global__ void k_layer(const float* __restrict__ xin, const float* __restrict__ RS,
                        const float* __restrict__ ew2, const float* __restrict__ eb2,
                        const float* __restrict__ nw1, const float* __restrict__ nb1,
                        const float* __restrict__ nw2, const float* __restrict__ nb2,
                        const float* __restrict__ ew1n, const float* __restrict__ eb1n,
                        float* __restrict__ xout, float* __restrict__ u,
                        float* __restrict__ v) {
  __shared__ float xa[8][HD], rs_s[8][HD], ag[8][HD], h1[8][HD], xo[8][HD];
  const int r0 = blockIdx.x * 8;
  for (int t = threadIdx.x; t < 8 * HD; t += 512) {
    int r = t >> 7, c = t & 127;
    xa[r][c]   = xin[(r0 + r) * HD + c];
    rs_s[r][c] = RS[(r0 + r) * HD + c];
  }
  __syncthreads();
  const int n = threadIdx.x & 127, rs4 = threadIdx.x >> 7;
  for (int rr = rs4; rr < 8; rr += 4) {            // aggr
    float acc = 512.0f * eb2[n];
    for (int k = 0; k < HD; ++k)
      acc += rs_s[rr][k] * ew2[k * HD + n];
    ag[rr][n] = acc;
  }
  __syncthreads();
  for (int rr = rs4; rr < 8; rr += 4) {            // node MLP layer 1
    float acc = nb1[n];
    for (int k = 0; k < HD; ++k)
      acc += xa[rr][k] * nw1[k * HD + n];
    for (int k = 0; k < HD; ++k)
      acc += ag[rr][k] * nw1[(HD + k) * HD + n];
    h1[rr][n] = fmaxf(acc, 0.0f);
  }
  __syncthreads();
  for (int rr = rs4; rr < 8; rr += 4) {            // node MLP layer 2
    float acc = nb2[n];
    for (int k = 0; k < HD; ++k)
      acc += h1[rr][k] * nw2[k * HD + n];
    xo[rr][n] = acc;
    xout[(r0 + rr) * HD + n] = acc;
  }
  __syncthreads();
  const bool isBird = (r0 < NB);                   // u/v for next layer
  const float* W = isBird ? ew1n : (ew1n + HD * HD);
  for (int rr = rs4; rr < 8; rr += 4) {
    float acc = isBird ? eb1n[n] : 0.0f;
    for (int k = 0; k < HD; ++k)
      acc += xo[rr][k] * W[k * HD + n];
    int row = r0 + rr;
    if (isBird) u[row * HD + n] = acc;
    else        v[(row - NB) * HD + n] = acc;
  }
}

// ---------------------------------------------------------------------------
// Last layer, bird rows only (color xout is dead): aggr + node MLP + gnn
// scores + mask/gather epilogue, writing d_out directly.
// 64 blocks x 512 threads, 8 bird rows each.
// ---------------------------------------------------------------------------
__global__ void k_last(const float* __restrict__ xin, const float* __restrict__ RS,
                       const float* __restrict__ ew2, const float* __restrict__ eb2,
                       const float* __restrict__ nw1, const float* __restrict__ nb1,
                       const float* __restrict__ nw2, const float* __restrict__ nb2,
                       const float* __restrict__ cpw, const float* __restrict__ cpb,
                       const float* __restrict__ probs, const int* __restrict__ idx,
                       float* __restrict__ out) {
  __shared__ float xa[8][HD], rs_s[8][HD], ag[8][HD], h1[8][HD], xo[8][HD];
  __shared__ float comb[8][NC];   // 16 KB
  const int r0 = blockIdx.x * 8;  // bird rows only
  for (int t = threadIdx.x; t < 8 * HD; t += 512) {
    int r = t >> 7, c = t & 127;
    xa[r][c]   = xin[(r0 + r) * HD + c];
    rs_s[r][c] = RS[(r0 + r) * HD + c];
  }
  __syncthreads();
  const int n = threadIdx.x & 127, rs4 = threadIdx.x >> 7;
  for (int rr = rs4; rr < 8; rr += 4) {
    float acc = 512.0f * eb2[n];
    for (int k = 0; k < HD; ++k)
      acc += rs_s[rr][k] * ew2[k * HD + n];
    ag[rr][n] = acc;
  }
  __syncthreads();
  for (int rr = rs4; rr < 8; rr += 4) {
    float acc = nb1[n];
    for (int k = 0; k < HD; ++k)
      acc += xa[rr][k] * nw1[k * HD + n];
    for (int k = 0; k < HD; ++k)
      acc += ag[rr][k] * nw1[(HD + k) * HD + n];
    h1[rr][n] = fmaxf(acc, 0.0f);
  }
  __syncthreads();
  for (int rr = rs4; rr < 8; rr += 4) {
    float acc = nb2[n];
    for (int k = 0; k < HD; ++k)
      acc += h1[rr][k] * nw2[k * HD + n];
    xo[rr][n] = acc;
  }
  __syncthreads();
  // gnn scores + combine with probs: thread c handles column c for all 8 rows
  const int c = threadIdx.x;
  float accs[8];
#pragma unroll
  for (int r = 0; r < 8; ++r) accs[r] = cpb[c];
  for (int k = 0; k < HD; ++k) {
    float w = cpw[k * NC + c];
#pragma unroll
    for (int r = 0; r < 8; ++r) accs[r] += xo[r][k] * w;
  }
#pragma unroll
  for (int r = 0; r < 8; ++r)
    comb[r][c] = accs[r] * probs[(r0 + r) * NC + c];
  __syncthreads();
  // cost[i][j] = 1 - comb[i][idx[i][j]]
  for (int t = threadIdx.x; t < 8 * NC; t += 512) {
    int r = t >> 9, j = t & 511;
    int cc = idx[(r0 + r) * NC + j];
    out[(r0 + r) * NC + j] = 1.0f - comb[r][cc];
  }
}

extern "C" void kernel_launch(void* const* d_in, const int* in_sizes, int n_in,
                              void* d_out, int out_size, void* d_ws, size_t ws_size,
                              hipStream_t stream) {
  const float* probs = (const float*)d_in[0];
  const float* npw   = (const float*)d_in[1];
  const float* npb   = (const float*)d_in[2];
  const float* ew1   = (const float*)d_in[3];
  const float* eb1   = (const float*)d_in[4];
  const float* ew2   = (const float*)d_in[5];
  const float* eb2   = (const float*)d_in[6];
  const float* nw1   = (const float*)d_in[7];
  const float* nb1   = (const float*)d_in[8];
  const float* nw2   = (const float*)d_in[9];
  const float* nb2   = (const float*)d_in[10];
  const float* cpw   = (const float*)d_in[11];
  const float* cpb   = (const float*)d_in[12];
  float* out = (float*)d_out;

  float* x0 = (float*)d_ws;        // 1024*128
  float* x1 = x0 + NN * HD;        // 1024*128
  float* u  = x1 + NN * HD;        // 512*128
  float* v  = u + NB * HD;         // 512*128
  float* RS = v + NC * HD;         // 1024*128
  int*  idx = (int*)(RS + NN * HD);// 512*512 ints

  k_sort<<<512, 512, 0, stream>>>(probs, idx);
  k_init<<<128, 512, 0, stream>>>(probs, npw, npb, ew1, eb1, x0, u, v);

  // layer 0: xin=x0 -> xout=x1, u/v for layer 1
  k_RS   <<<256, 256, 0, stream>>>(u, v, RS);
  k_layer<<<128, 512, 0, stream>>>(x0, RS, ew2, eb2, nw1, nb1, nw2, nb2,
                                   ew1 + 2 * HD * HD, eb1 + HD, x1, u, v);
  // layer 1: xin=x1 -> xout=x0, u/v for layer 2
  k_RS   <<<256, 256, 0, stream>>>(u, v, RS);
  k_layer<<<128, 512, 0, stream>>>(x1, RS, ew2 + HD * HD, eb2 + HD,
                                   nw1 + 2 * HD * HD, nb1 + HD, nw2 + HD * HD, nb2 + HD,
                                   ew1 + 4 * HD * HD, eb1 + 2 * HD, x0, u, v);
  // layer 2: bird rows only, fused through to d_out
  k_RS   <<<256, 256, 0, stream>>>(u, v, RS);
  k_last <<<64, 512, 0, stream>>>(x0, RS, ew2 + 2 * HD * HD, eb2 + 2 * HD,
                                  nw1 + 4 * HD * HD, nb1 + 2 * HD,
                                  nw2 + 2 * HD * HD, nb2 + 2 * HD,
                                  cpw, cpb, probs, idx, out);
}